// Round 16
// baseline (47.042 us; speedup 1.0000x reference)
//
#include <hip/hip_runtime.h>
#include <math.h>

#define PI_F 3.14159265358979323846f
typedef float floatx4 __attribute__((ext_vector_type(4)));

// ---- DPP reduction ladders (HW-validated R7/R8/R11/R13/R14) ----
template <int CTRL>
__device__ __forceinline__ float dpp_addf(float v) {
  int p = __builtin_amdgcn_update_dpp(0, __float_as_int(v), CTRL, 0xF, 0xF, true);
  return v + __int_as_float(p);
}
__device__ __forceinline__ float red8(float v) {
  v = dpp_addf<0xB1>(v);
  v = dpp_addf<0x4E>(v);
  v = dpp_addf<0x104>(v);   // row_shl:4
  return v;
}
__device__ __forceinline__ float red16(float v) {
  v = dpp_addf<0xB1>(v);    // quad_perm xor1
  v = dpp_addf<0x4E>(v);    // quad_perm xor2
  v = dpp_addf<0x124>(v);   // row_ror:4
  v = dpp_addf<0x128>(v);   // row_ror:8
  return v;
}
__device__ __forceinline__ float red64(float v) {
  v = red16(v);
  v += __shfl_xor(v, 16);
  v += __shfl_xor(v, 32);
  return v;
}

// Kernel 1: Zernike pooling (= R13/R14 structure) + fused BN-stats atomics:
// leaders also atomicAdd value and value^2 into stats[1152] (sums | sumsq).
__global__ __launch_bounds__(256) void zpool_kernel(const float* __restrict__ x,
                                                    float* __restrict__ pooled,
                                                    float* __restrict__ stats) {
  const int blk = blockIdx.x;              // 0..3071
  const int b = blk / 3;
  const int rank = blk - b * 3;
  const floatx4* __restrict__ src4 =
      reinterpret_cast<const floatx4*>(x) + (size_t)b * 6144 + rank * 8;

  const int t = threadIdx.x;
  const int lane = t & 63;
  const int w = t >> 6;                    // wave 0..3
  const int cq = lane >> 3;                // channel quad 0..7 (8 contiguous lanes)
  const int s = lane & 7;                  // pixel-slot within group
  const int xcol = (8 * w + s) & 15;
  const int hoff = w >> 1;                 // 0 or 1
  const float X = -1.0f + (float)xcol * (2.0f / 15.0f);   // thread-constant

  __shared__ float p1[4][8][12];
  __shared__ float cxy[8][8];
  __shared__ float p2[4][8][40];

  floatx4 f[8];
#pragma unroll
  for (int i = 0; i < 8; ++i)
    f[i] = src4[(32 * i + 8 * w + s) * 24 + cq];

  // ---- Pass 1: centroid sums ----
  floatx4 s0v = {0, 0, 0, 0}, syv = {0, 0, 0, 0};
#pragma unroll
  for (int i = 0; i < 8; ++i) {
    const float Y = -1.0f + (float)(2 * i + hoff) * (2.0f / 15.0f);
    s0v += f[i];
    syv += f[i] * Y;
  }
  floatx4 sxv = s0v * X;
#pragma unroll
  for (int c = 0; c < 4; ++c) {
    s0v[c] = red8(s0v[c]);
    sxv[c] = red8(sxv[c]);
    syv[c] = red8(syv[c]);
  }
  if (s == 0) {
#pragma unroll
    for (int c = 0; c < 4; ++c) {
      p1[w][cq][c] = s0v[c];
      p1[w][cq][4 + c] = sxv[c];
      p1[w][cq][8 + c] = syv[c];
    }
  }
  __syncthreads();
  if (t < 8) {
#pragma unroll
    for (int c = 0; c < 4; ++c) {
      float S0 = 0.0f, SX = 0.0f, SY = 0.0f;
#pragma unroll
      for (int w2 = 0; w2 < 4; ++w2) {
        S0 += p1[w2][t][c];
        SX += p1[w2][t][4 + c];
        SY += p1[w2][t][8 + c];
      }
      const float inv = 1.0f / (S0 + 1e-6f);
      cxy[t][c] = SX * inv;
      cxy[t][4 + c] = SY * inv;
    }
  }
  __syncthreads();
  floatx4 cx, cy;
#pragma unroll
  for (int c = 0; c < 4; ++c) { cx[c] = cxy[cq][c]; cy[c] = cxy[cq][4 + c]; }

  const floatx4 Xs = X - cx;
  const floatx4 Xs2 = Xs * Xs;
  const floatx4 Xs3 = Xs2 * Xs;
  const floatx4 lim = 1.0f - Xs2;          // mask: Ys^2 <= 1 - Xs^2

  // ---- Pass 2: moments m_j = sum g * Ys^j ----
  floatx4 m0 = {0,0,0,0}, m1 = {0,0,0,0}, m2 = {0,0,0,0}, m3 = {0,0,0,0};
#pragma unroll
  for (int i = 0; i < 8; ++i) {
    const float Y = -1.0f + (float)(2 * i + hoff) * (2.0f / 15.0f);
    const floatx4 Ys = Y - cy;
    const floatx4 Ys2 = Ys * Ys;
    floatx4 g;
#pragma unroll
    for (int c = 0; c < 4; ++c) g[c] = (Ys2[c] <= lim[c]) ? f[i][c] : 0.0f;
    const floatx4 gy = g * Ys;
    m0 += g;
    m1 += gy;
    m2 += gy * Ys;
    m3 += gy * Ys2;
  }

  floatx4 S[10];
  S[0] = m0;        S[1] = Xs * m0;  S[2] = Xs2 * m0; S[3] = Xs3 * m0;
  S[4] = m1;        S[5] = Xs * m1;  S[6] = Xs2 * m1;
  S[7] = m2;        S[8] = Xs * m2;  S[9] = m3;
#pragma unroll
  for (int v = 0; v < 10; ++v)
#pragma unroll
    for (int c = 0; c < 4; ++c) S[v][c] = red8(S[v][c]);

  if (s == 0) {
#pragma unroll
    for (int v = 0; v < 10; ++v)
#pragma unroll
      for (int c = 0; c < 4; ++c) p2[w][cq][v * 4 + c] = S[v][c];
  }
  __syncthreads();

  if (t < 32) {
    const int fcq = t >> 2, comp = t & 3;
    float T[10];
#pragma unroll
    for (int v = 0; v < 10; ++v) {
      float acc = 0.0f;
#pragma unroll
      for (int w2 = 0; w2 < 4; ++w2) acc += p2[w2][fcq][v * 4 + comp];
      T[v] = acc;
    }
    const float S00 = T[0], S10 = T[1], S20 = T[2], S30 = T[3];
    const float S01 = T[4], S11 = T[5], S21 = T[6];
    const float S02 = T[7], S12 = T[8], S03 = T[9];
    const float a0 = S00;
    const float a1 = S10, b1 = S01;
    const float a2 = 2.0f * (S20 + S02) - S00;
    const float a3 = S20 - S02, b3 = 2.0f * S11;
    const float a4 = 3.0f * (S30 + S12) - 2.0f * S10;
    const float b4 = 3.0f * (S21 + S03) - 2.0f * S01;
    const float a5 = S30 - 3.0f * S12;
    const float b5 = 3.0f * S21 - S03;
    const int fbase = rank * 192 + t;
    float* po = pooled + (size_t)b * 576 + fbase;
    const float INV = 1.0f / 65536.0f;     // (1/256)^2 for the means
    float vals[6];
    vals[0] = (1.0f / PI_F) * sqrtf(a0 * a0 * INV + 1e-12f);
    vals[1] = (2.0f / PI_F) * sqrtf(fmaf(a1, a1, b1 * b1) * INV + 1e-12f);
    vals[2] = (3.0f / PI_F) * sqrtf(a2 * a2 * INV + 1e-12f);
    vals[3] = (3.0f / PI_F) * sqrtf(fmaf(a3, a3, b3 * b3) * INV + 1e-12f);
    vals[4] = (4.0f / PI_F) * sqrtf(fmaf(a4, a4, b4 * b4) * INV + 1e-12f);
    vals[5] = (4.0f / PI_F) * sqrtf(fmaf(a5, a5, b5 * b5) * INV + 1e-12f);
#pragma unroll
    for (int v = 0; v < 6; ++v) {
      po[v * 32] = vals[v];
      atomicAdd(&stats[fbase + v * 32], vals[v]);              // sum
      atomicAdd(&stats[576 + fbase + v * 32], vals[v] * vals[v]);  // sumsq
    }
  }
}

// Kernel 2 (final): head with in-kernel BN finalize. Lane's feature
// k = lane+64j: a,c derived from stats (L2-hot) -- no bn kernel, no extra sync.
__global__ __launch_bounds__(64) void head_kernel(const float* __restrict__ pooled,
                                                  const float* __restrict__ stats,
                                                  const float* __restrict__ gamma,
                                                  const float* __restrict__ beta,
                                                  const float* __restrict__ Wl,
                                                  const float* __restrict__ bl,
                                                  float* __restrict__ out) {
  const int row = blockIdx.x;     // 0..1023
  const int lane = threadIdx.x;   // 0..63
  const float* pr = pooled + (size_t)row * 576;

  float av[9], cv[9];
#pragma unroll
  for (int j = 0; j < 9; ++j) {
    const int k = lane + 64 * j;
    const float mean = stats[k] * (1.0f / 1024.0f);
    const float var = fmaf(-mean, mean, stats[576 + k] * (1.0f / 1024.0f));
    const float istd = rsqrtf(var + 1e-5f);
    av[j] = gamma[k] * istd;
    cv[j] = fmaf(-mean, av[j], beta[k]);
  }

  float acc0 = 0, acc1 = 0, acc2 = 0, acc3 = 0, acc4 = 0;
  float acc5 = 0, acc6 = 0, acc7 = 0, acc8 = 0, acc9 = 0;
#pragma unroll
  for (int j = 0; j < 9; ++j) {
    const int k = lane + 64 * j;
    const float z = fmaf(pr[k], av[j], cv[j]);
    acc0 = fmaf(z, Wl[0 * 576 + k], acc0);
    acc1 = fmaf(z, Wl[1 * 576 + k], acc1);
    acc2 = fmaf(z, Wl[2 * 576 + k], acc2);
    acc3 = fmaf(z, Wl[3 * 576 + k], acc3);
    acc4 = fmaf(z, Wl[4 * 576 + k], acc4);
    acc5 = fmaf(z, Wl[5 * 576 + k], acc5);
    acc6 = fmaf(z, Wl[6 * 576 + k], acc6);
    acc7 = fmaf(z, Wl[7 * 576 + k], acc7);
    acc8 = fmaf(z, Wl[8 * 576 + k], acc8);
    acc9 = fmaf(z, Wl[9 * 576 + k], acc9);
  }
  acc0 = red64(acc0); acc1 = red64(acc1); acc2 = red64(acc2);
  acc3 = red64(acc3); acc4 = red64(acc4); acc5 = red64(acc5);
  acc6 = red64(acc6); acc7 = red64(acc7); acc8 = red64(acc8);
  acc9 = red64(acc9);
  if (lane == 0) {
    float* o = out + (size_t)row * 10;
    o[0] = acc0 + bl[0]; o[1] = acc1 + bl[1]; o[2] = acc2 + bl[2];
    o[3] = acc3 + bl[3]; o[4] = acc4 + bl[4]; o[5] = acc5 + bl[5];
    o[6] = acc6 + bl[6]; o[7] = acc7 + bl[7]; o[8] = acc8 + bl[8];
    o[9] = acc9 + bl[9];
  }
}

extern "C" void kernel_launch(void* const* d_in, const int* in_sizes, int n_in,
                              void* d_out, int out_size, void* d_ws, size_t ws_size,
                              hipStream_t stream) {
  const float* x     = (const float*)d_in[0];
  const float* gamma = (const float*)d_in[1];
  const float* beta  = (const float*)d_in[2];
  const float* Wl    = (const float*)d_in[3];
  const float* bl    = (const float*)d_in[4];
  float* out = (float*)d_out;

  float* pooled = (float*)d_ws;            // 1024*576 floats
  float* stats = pooled + 576 * 1024;      // 1152 floats: sums[576] | sumsq[576]

  hipMemsetAsync(stats, 0, 1152 * sizeof(float), stream);
  zpool_kernel<<<3072, 256, 0, stream>>>(x, pooled, stats);
  head_kernel<<<1024, 64, 0, stream>>>(pooled, stats, gamma, beta, Wl, bl, out);
}

// Round 17
// 34.150 us; speedup vs baseline: 1.3775x; 1.3775x over previous
//
#include <hip/hip_runtime.h>
#include <math.h>

#define PI_F 3.14159265358979323846f
typedef float floatx4 __attribute__((ext_vector_type(4)));

// ---- DPP reduction ladders (HW-validated R7/R8/R11/R13/R14) ----
template <int CTRL>
__device__ __forceinline__ float dpp_addf(float v) {
  int p = __builtin_amdgcn_update_dpp(0, __float_as_int(v), CTRL, 0xF, 0xF, true);
  return v + __int_as_float(p);
}
__device__ __forceinline__ float red8(float v) {
  v = dpp_addf<0xB1>(v);
  v = dpp_addf<0x4E>(v);
  v = dpp_addf<0x104>(v);   // row_shl:4
  return v;
}
__device__ __forceinline__ float red16(float v) {
  v = dpp_addf<0xB1>(v);    // quad_perm xor1
  v = dpp_addf<0x4E>(v);    // quad_perm xor2
  v = dpp_addf<0x124>(v);   // row_ror:4
  v = dpp_addf<0x128>(v);   // row_ror:8
  return v;
}
// 64-lane sum: DPP for the 16-lane part, shfl for the 16/32 crossings.
__device__ __forceinline__ float red64(float v) {
  v = red16(v);
  v += __shfl_xor(v, 16);
  v += __shfl_xor(v, 32);
  return v;
}

// Kernel 1: Zernike pooling, register-resident (NO LDS staging).
// (= round-13/14 best; NO stats atomics -- R16 showed they serialize)
__global__ __launch_bounds__(256) void zpool_kernel(const float* __restrict__ x,
                                                    float* __restrict__ pooled) {
  const int blk = blockIdx.x;              // 0..3071
  const int b = blk / 3;
  const int rank = blk - b * 3;
  const floatx4* __restrict__ src4 =
      reinterpret_cast<const floatx4*>(x) + (size_t)b * 6144 + rank * 8;

  const int t = threadIdx.x;
  const int lane = t & 63;
  const int w = t >> 6;                    // wave 0..3
  const int cq = lane >> 3;                // channel quad 0..7 (8 contiguous lanes)
  const int s = lane & 7;                  // pixel-slot within group
  const int xcol = (8 * w + s) & 15;
  const int hoff = w >> 1;                 // 0 or 1
  const float X = -1.0f + (float)xcol * (2.0f / 15.0f);   // thread-constant

  __shared__ float p1[4][8][12];
  __shared__ float cxy[8][8];
  __shared__ float p2[4][8][40];

  floatx4 f[8];
#pragma unroll
  for (int i = 0; i < 8; ++i)
    f[i] = src4[(32 * i + 8 * w + s) * 24 + cq];

  // ---- Pass 1: centroid sums ----
  floatx4 s0v = {0, 0, 0, 0}, syv = {0, 0, 0, 0};
#pragma unroll
  for (int i = 0; i < 8; ++i) {
    const float Y = -1.0f + (float)(2 * i + hoff) * (2.0f / 15.0f);
    s0v += f[i];
    syv += f[i] * Y;
  }
  floatx4 sxv = s0v * X;
#pragma unroll
  for (int c = 0; c < 4; ++c) {
    s0v[c] = red8(s0v[c]);
    sxv[c] = red8(sxv[c]);
    syv[c] = red8(syv[c]);
  }
  if (s == 0) {
#pragma unroll
    for (int c = 0; c < 4; ++c) {
      p1[w][cq][c] = s0v[c];
      p1[w][cq][4 + c] = sxv[c];
      p1[w][cq][8 + c] = syv[c];
    }
  }
  __syncthreads();
  if (t < 8) {
#pragma unroll
    for (int c = 0; c < 4; ++c) {
      float S0 = 0.0f, SX = 0.0f, SY = 0.0f;
#pragma unroll
      for (int w2 = 0; w2 < 4; ++w2) {
        S0 += p1[w2][t][c];
        SX += p1[w2][t][4 + c];
        SY += p1[w2][t][8 + c];
      }
      const float inv = 1.0f / (S0 + 1e-6f);
      cxy[t][c] = SX * inv;
      cxy[t][4 + c] = SY * inv;
    }
  }
  __syncthreads();
  floatx4 cx, cy;
#pragma unroll
  for (int c = 0; c < 4; ++c) { cx[c] = cxy[cq][c]; cy[c] = cxy[cq][4 + c]; }

  const floatx4 Xs = X - cx;
  const floatx4 Xs2 = Xs * Xs;
  const floatx4 Xs3 = Xs2 * Xs;
  const floatx4 lim = 1.0f - Xs2;          // mask: Ys^2 <= 1 - Xs^2

  // ---- Pass 2: moments m_j = sum g * Ys^j ----
  floatx4 m0 = {0,0,0,0}, m1 = {0,0,0,0}, m2 = {0,0,0,0}, m3 = {0,0,0,0};
#pragma unroll
  for (int i = 0; i < 8; ++i) {
    const float Y = -1.0f + (float)(2 * i + hoff) * (2.0f / 15.0f);
    const floatx4 Ys = Y - cy;
    const floatx4 Ys2 = Ys * Ys;
    floatx4 g;
#pragma unroll
    for (int c = 0; c < 4; ++c) g[c] = (Ys2[c] <= lim[c]) ? f[i][c] : 0.0f;
    const floatx4 gy = g * Ys;
    m0 += g;
    m1 += gy;
    m2 += gy * Ys;
    m3 += gy * Ys2;
  }

  floatx4 S[10];
  S[0] = m0;        S[1] = Xs * m0;  S[2] = Xs2 * m0; S[3] = Xs3 * m0;
  S[4] = m1;        S[5] = Xs * m1;  S[6] = Xs2 * m1;
  S[7] = m2;        S[8] = Xs * m2;  S[9] = m3;
#pragma unroll
  for (int v = 0; v < 10; ++v)
#pragma unroll
    for (int c = 0; c < 4; ++c) S[v][c] = red8(S[v][c]);

  if (s == 0) {
#pragma unroll
    for (int v = 0; v < 10; ++v)
#pragma unroll
      for (int c = 0; c < 4; ++c) p2[w][cq][v * 4 + c] = S[v][c];
  }
  __syncthreads();

  if (t < 32) {
    const int fcq = t >> 2, comp = t & 3;
    float T[10];
#pragma unroll
    for (int v = 0; v < 10; ++v) {
      float acc = 0.0f;
#pragma unroll
      for (int w2 = 0; w2 < 4; ++w2) acc += p2[w2][fcq][v * 4 + comp];
      T[v] = acc;
    }
    const float S00 = T[0], S10 = T[1], S20 = T[2], S30 = T[3];
    const float S01 = T[4], S11 = T[5], S21 = T[6];
    const float S02 = T[7], S12 = T[8], S03 = T[9];
    const float a0 = S00;
    const float a1 = S10, b1 = S01;
    const float a2 = 2.0f * (S20 + S02) - S00;
    const float a3 = S20 - S02, b3 = 2.0f * S11;
    const float a4 = 3.0f * (S30 + S12) - 2.0f * S10;
    const float b4 = 3.0f * (S21 + S03) - 2.0f * S01;
    const float a5 = S30 - 3.0f * S12;
    const float b5 = 3.0f * S21 - S03;
    float* po = pooled + (size_t)b * 576 + rank * 192 + t;
    const float INV = 1.0f / 65536.0f;     // (1/256)^2 for the means
    po[0]   = (1.0f / PI_F) * sqrtf(a0 * a0 * INV + 1e-12f);
    po[32]  = (2.0f / PI_F) * sqrtf(fmaf(a1, a1, b1 * b1) * INV + 1e-12f);
    po[64]  = (3.0f / PI_F) * sqrtf(a2 * a2 * INV + 1e-12f);
    po[96]  = (3.0f / PI_F) * sqrtf(fmaf(a3, a3, b3 * b3) * INV + 1e-12f);
    po[128] = (4.0f / PI_F) * sqrtf(fmaf(a4, a4, b4 * b4) * INV + 1e-12f);
    po[160] = (4.0f / PI_F) * sqrtf(fmaf(a5, a5, b5 * b5) * INV + 1e-12f);
  }
}

// Kernel 2: BN stats, float4 edition (= round-14 winner; unchanged).
__global__ __launch_bounds__(256) void bn_stats_kernel(const float* __restrict__ pooled,
                                                       const float* __restrict__ gamma,
                                                       const float* __restrict__ beta,
                                                       float* __restrict__ a,
                                                       float* __restrict__ c) {
  const int f0 = blockIdx.x * 4;           // 0,4,...,572
  const int t = threadIdx.x;               // 256
  const floatx4* __restrict__ p =
      reinterpret_cast<const floatx4*>(pooled + f0);   // row stride 144 float4
  floatx4 s = {0, 0, 0, 0}, q = {0, 0, 0, 0};
#pragma unroll
  for (int j = 0; j < 4; ++j) {
    const floatx4 v = p[(size_t)(t + 256 * j) * 144];
    s += v;
    q += v * v;
  }
#pragma unroll
  for (int cc = 0; cc < 4; ++cc) {
    s[cc] = red64(s[cc]);
    q[cc] = red64(q[cc]);
  }
  __shared__ float ls[4][8];
  const int w = t >> 6;
  if ((t & 63) == 0) {
#pragma unroll
    for (int cc = 0; cc < 4; ++cc) { ls[w][cc] = s[cc]; ls[w][4 + cc] = q[cc]; }
  }
  __syncthreads();
  if (t < 4) {                             // thread t -> feature f0+t
    float S = 0.0f, Q = 0.0f;
#pragma unroll
    for (int i = 0; i < 4; ++i) { S += ls[i][t]; Q += ls[i][4 + t]; }
    const float mean = S * (1.0f / 1024.0f);
    const float var = fmaf(-mean, mean, Q * (1.0f / 1024.0f));  // biased var
    const float istd = rsqrtf(var + 1e-5f);
    const float av = gamma[f0 + t] * istd;
    a[f0 + t] = av;
    c[f0 + t] = fmaf(-mean, av, beta[f0 + t]);
  }
}

// Kernel 3: head (= round-14 winner: 1 row per wave, DPP reduce; unchanged).
__global__ __launch_bounds__(64) void head_kernel(const float* __restrict__ pooled,
                                                  const float* __restrict__ a,
                                                  const float* __restrict__ c,
                                                  const float* __restrict__ Wl,
                                                  const float* __restrict__ bl,
                                                  float* __restrict__ out) {
  const int row = blockIdx.x;     // 0..1023
  const int lane = threadIdx.x;   // 0..63
  const float* pr = pooled + (size_t)row * 576;
  float acc0 = 0, acc1 = 0, acc2 = 0, acc3 = 0, acc4 = 0;
  float acc5 = 0, acc6 = 0, acc7 = 0, acc8 = 0, acc9 = 0;
#pragma unroll
  for (int j = 0; j < 9; ++j) {
    const int k = lane + 64 * j;
    const float z = fmaf(pr[k], a[k], c[k]);
    acc0 = fmaf(z, Wl[0 * 576 + k], acc0);
    acc1 = fmaf(z, Wl[1 * 576 + k], acc1);
    acc2 = fmaf(z, Wl[2 * 576 + k], acc2);
    acc3 = fmaf(z, Wl[3 * 576 + k], acc3);
    acc4 = fmaf(z, Wl[4 * 576 + k], acc4);
    acc5 = fmaf(z, Wl[5 * 576 + k], acc5);
    acc6 = fmaf(z, Wl[6 * 576 + k], acc6);
    acc7 = fmaf(z, Wl[7 * 576 + k], acc7);
    acc8 = fmaf(z, Wl[8 * 576 + k], acc8);
    acc9 = fmaf(z, Wl[9 * 576 + k], acc9);
  }
  acc0 = red64(acc0); acc1 = red64(acc1); acc2 = red64(acc2);
  acc3 = red64(acc3); acc4 = red64(acc4); acc5 = red64(acc5);
  acc6 = red64(acc6); acc7 = red64(acc7); acc8 = red64(acc8);
  acc9 = red64(acc9);
  if (lane == 0) {
    float* o = out + (size_t)row * 10;
    o[0] = acc0 + bl[0]; o[1] = acc1 + bl[1]; o[2] = acc2 + bl[2];
    o[3] = acc3 + bl[3]; o[4] = acc4 + bl[4]; o[5] = acc5 + bl[5];
    o[6] = acc6 + bl[6]; o[7] = acc7 + bl[7]; o[8] = acc8 + bl[8];
    o[9] = acc9 + bl[9];
  }
}

extern "C" void kernel_launch(void* const* d_in, const int* in_sizes, int n_in,
                              void* d_out, int out_size, void* d_ws, size_t ws_size,
                              hipStream_t stream) {
  const float* x     = (const float*)d_in[0];
  const float* gamma = (const float*)d_in[1];
  const float* beta  = (const float*)d_in[2];
  const float* Wl    = (const float*)d_in[3];
  const float* bl    = (const float*)d_in[4];
  float* out = (float*)d_out;

  float* pooled = (float*)d_ws;            // 1024*576 floats
  float* a = pooled + 576 * 1024;          // 576 floats
  float* c = a + 576;                      // 576 floats

  zpool_kernel<<<3072, 256, 0, stream>>>(x, pooled);
  bn_stats_kernel<<<144, 256, 0, stream>>>(pooled, gamma, beta, a, c);
  head_kernel<<<1024, 64, 0, stream>>>(pooled, a, c, Wl, bl, out);
}